// Round 9
// baseline (201.566 us; speedup 1.0000x reference)
//
#include <hip/hip_runtime.h>
#include <hip/hip_bf16.h>
#include <math.h>

#define FIN 64
#define HID 64
#define FOUT 40
#define H2S_STRIDE 64   // bf16 elements; 128 B row stride, one cache line per row
#define LDSU 36         // uint stride per staged LDS row (144 B): pad breaks conflicts
#define CCHUNK 4096     // edges per partition block
#define MAXBUCK 400     // LDS histogram capacity (>= nbuck = ceil(N/256))

typedef __attribute__((ext_vector_type(8))) short short8;
typedef __attribute__((ext_vector_type(4))) float f32x4;

__device__ __forceinline__ float bf_lo(unsigned u) { return __uint_as_float(u << 16); }
__device__ __forceinline__ float bf_hi(unsigned u) { return __uint_as_float(u & 0xFFFF0000u); }

// round-to-nearest-even fp32 -> bf16 bits
__device__ __forceinline__ unsigned short bfbits(float f) {
    unsigned u = __float_as_uint(f);
    u += 0x7FFFu + ((u >> 16) & 1u);
    return (unsigned short)(u >> 16);
}
__device__ __forceinline__ unsigned pk_bf16(float lo, float hi) {
    unsigned a = __float_as_uint(lo), b = __float_as_uint(hi);
    a += 0x7FFFu + ((a >> 16) & 1u);
    b += 0x7FFFu + ((b >> 16) & 1u);
    return (a >> 16) | (b & 0xFFFF0000u);
}

// ================= CSR build: two-level counting sort (no global atomics) =================
// bucket = dst >> 8 (256 nodes per bucket). Pack: src (20 bits) | local_dst << 20.

__global__ __launch_bounds__(256) void bucket_hist_kernel(const int* __restrict__ dst,
        int* __restrict__ cnt, int E, int nbuck, int nblkc) {
    __shared__ int hist[MAXBUCK];
    int tid = threadIdx.x;
    for (int i = tid; i < nbuck; i += 256) hist[i] = 0;
    __syncthreads();
    int base = blockIdx.x * CCHUNK;
    int lim = min(CCHUNK, E - base);
    for (int i = tid; i < lim; i += 256)
        atomicAdd(&hist[dst[base + i] >> 8], 1);
    __syncthreads();
    for (int b = tid; b < nbuck; b += 256)
        cnt[b * nblkc + blockIdx.x] = hist[b];
}

__global__ __launch_bounds__(256) void bucket_colscan_kernel(int* __restrict__ cnt,
        int* __restrict__ total, int nblkc) {
    int b = blockIdx.x;
    int tid = threadIdx.x, lane = tid & 63, wid = tid >> 6;
    int v = (tid < nblkc) ? cnt[b * nblkc + tid] : 0;
    int incl = v;
    #pragma unroll
    for (int off = 1; off < 64; off <<= 1) {
        int t2 = __shfl_up(incl, off);
        if (lane >= off) incl += t2;
    }
    __shared__ int ws[4];
    if (lane == 63) ws[wid] = incl;
    __syncthreads();
    int woff = 0;
    for (int w2 = 0; w2 < wid; ++w2) woff += ws[w2];
    int excl = woff + incl - v;
    if (tid < nblkc) cnt[b * nblkc + tid] = excl;
    if (tid == 255) total[b] = woff + incl;
}

__global__ __launch_bounds__(512) void bucket_scan_kernel(const int* __restrict__ total,
        int* __restrict__ bucketStart, int nbuck, int* __restrict__ rowstart, int N) {
    int tid = threadIdx.x, lane = tid & 63, wid = tid >> 6;
    int v = (tid < nbuck) ? total[tid] : 0;
    int incl = v;
    #pragma unroll
    for (int off = 1; off < 64; off <<= 1) {
        int t2 = __shfl_up(incl, off);
        if (lane >= off) incl += t2;
    }
    __shared__ int ws[8];
    if (lane == 63) ws[wid] = incl;
    __syncthreads();
    int woff = 0;
    for (int w2 = 0; w2 < wid; ++w2) woff += ws[w2];
    int excl = woff + incl - v;
    if (tid <= nbuck) bucketStart[tid] = excl;
    if (tid == nbuck) rowstart[N] = excl;     // == E
}

__global__ __launch_bounds__(256) void partition_kernel(const int* __restrict__ src,
        const int* __restrict__ dst, const int* __restrict__ cnt,
        const int* __restrict__ bucketStart, unsigned* __restrict__ ebuf,
        int E, int nbuck, int nblkc) {
    __shared__ int cur[MAXBUCK];
    int tid = threadIdx.x;
    int r = blockIdx.x;
    for (int b = tid; b < nbuck; b += 256)
        cur[b] = bucketStart[b] + cnt[b * nblkc + r];
    __syncthreads();
    int base = r * CCHUNK;
    int lim = min(CCHUNK, E - base);
    for (int i = tid; i < lim; i += 256) {
        int d = dst[base + i];
        int s = src[base + i];
        int b = d >> 8;
        int pos = atomicAdd(&cur[b], 1);       // LDS atomic
        ebuf[pos] = (unsigned)s | ((unsigned)(d & 255) << 20);
    }
}

__global__ __launch_bounds__(256) void build_csr_kernel(const unsigned* __restrict__ ebuf,
        const int* __restrict__ bucketStart, int* __restrict__ rowstart,
        float* __restrict__ dinv, int* __restrict__ csr_src, int n) {
    __shared__ int hist[256];
    __shared__ int cur[256];
    __shared__ int ws[4];
    __shared__ int stage[4096];
    int b = blockIdx.x, tid = threadIdx.x;
    int base = bucketStart[b];
    int m = bucketStart[b + 1] - base;
    hist[tid] = 0;
    __syncthreads();
    for (int i = tid; i < m; i += 256)
        atomicAdd(&hist[ebuf[base + i] >> 20], 1);
    __syncthreads();
    int deg = hist[tid];
    int lane = tid & 63, wid = tid >> 6;
    int incl = deg;
    #pragma unroll
    for (int off = 1; off < 64; off <<= 1) {
        int t2 = __shfl_up(incl, off);
        if (lane >= off) incl += t2;
    }
    if (lane == 63) ws[wid] = incl;
    __syncthreads();
    int woff = 0;
    for (int w2 = 0; w2 < wid; ++w2) woff += ws[w2];
    int excl = woff + incl - deg;
    int node = b * 256 + tid;
    if (node < n) {
        rowstart[node] = base + excl;
        dinv[node] = rsqrtf((float)deg + 1.0f);
    }
    cur[tid] = excl;
    __syncthreads();
    if (m <= 4096) {
        for (int i = tid; i < m; i += 256) {
            unsigned p = ebuf[base + i];
            int pos = atomicAdd(&cur[p >> 20], 1);
            stage[pos] = (int)(p & 0xFFFFFu);
        }
        __syncthreads();
        for (int i = tid; i < m; i += 256)
            csr_src[base + i] = stage[i];      // coalesced
    } else {
        for (int i = tid; i < m; i += 256) {
            unsigned p = ebuf[base + i];
            int pos = atomicAdd(&cur[p >> 20], 1);
            csr_src[base + pos] = (int)(p & 0xFFFFFu);
        }
    }
}

// ================= layer 1 GEMM (MFMA bf16): h1s = bf16( (x @ W1) * dinv ) =================

__global__ __launch_bounds__(256) void gemm1_mfma(const float* __restrict__ x,
        const float* __restrict__ W, const float* __restrict__ dinv,
        __hip_bfloat16* __restrict__ h, int n) {
    __shared__ unsigned As[64 * LDSU];
    int tid = threadIdx.x;
    int lane = tid & 63;
    int w = tid >> 6;
    int q = lane >> 4;        // 0..3 k-block / row-quad
    int c = lane & 15;        // col within tile
    int nodeBase = blockIdx.x * 64;

    #pragma unroll
    for (int i = 0; i < 4; ++i) {
        int fidx = tid + 256 * i;          // float4 index 0..1023
        int row = fidx >> 4, c4 = fidx & 15;
        int node = nodeBase + row; if (node >= n) node = n - 1;
        float4 v = *(const float4*)(x + (size_t)node * 64 + c4 * 4);
        As[row * LDSU + c4 * 2 + 0] = pk_bf16(v.x, v.y);
        As[row * LDSU + c4 * 2 + 1] = pk_bf16(v.z, v.w);
    }
    short8 Bf[4][2];
    #pragma unroll
    for (int nt = 0; nt < 4; ++nt)
        #pragma unroll
        for (int kk = 0; kk < 2; ++kk)
            #pragma unroll
            for (int j = 0; j < 8; ++j)
                Bf[nt][kk][j] = (short)bfbits(W[(kk * 32 + q * 8 + j) * 64 + nt * 16 + c]);
    __syncthreads();

    f32x4 acc[4];
    #pragma unroll
    for (int nt = 0; nt < 4; ++nt) acc[nt] = (f32x4){0.f, 0.f, 0.f, 0.f};
    #pragma unroll
    for (int kk = 0; kk < 2; ++kk) {
        short8 a = *(const short8*)&As[(w * 16 + c) * LDSU + kk * 16 + q * 4];
        #pragma unroll
        for (int nt = 0; nt < 4; ++nt)
            acc[nt] = __builtin_amdgcn_mfma_f32_16x16x32_bf16(a, Bf[nt][kk], acc[nt], 0, 0, 0);
    }
    unsigned short* hu = (unsigned short*)h;
    #pragma unroll
    for (int r = 0; r < 4; ++r) {
        int node = nodeBase + w * 16 + q * 4 + r;
        if (node < n) {
            float dv = dinv[node];
            #pragma unroll
            for (int nt = 0; nt < 4; ++nt)
                hu[(size_t)node * 64 + nt * 16 + c] = bfbits(acc[nt][r] * dv);
        }
    }
}

// ================= gather layer 1 (quarter-wave: 4 edges per load, unroll x2) =========
// agg1b[d] = bf16( relu( (h1s[d] + sum_{e->d} h1s[src]) * dinv[d] + b1 ) )

__global__ __launch_bounds__(256) void gather1_kernel(const __hip_bfloat16* __restrict__ h1s,
        const int* __restrict__ rowstart, const int* __restrict__ csr_src,
        const float* __restrict__ dinv, const float* __restrict__ b,
        __hip_bfloat16* __restrict__ agg1, int n) {
    int tid = threadIdx.x;
    int node_nu = blockIdx.x * 4 + (tid >> 6);
    if (node_nu >= n) return;
    int node = __builtin_amdgcn_readfirstlane(node_nu);
    int lane = tid & 63;
    int q = lane >> 4;             // quarter 0..3 = which edge in the group
    int i = lane & 15;             // uint2 index within row (features 4i..4i+3)
    const uint2* hv = (const uint2*)h1s;     // 16 uint2 per row
    uint2 u_self = hv[(size_t)node * 16 + i];
    int beg = rowstart[node], end = rowstart[node + 1];
    float a0 = 0.f, a1 = 0.f, a2 = 0.f, a3 = 0.f;
    float c0 = 0.f, c1 = 0.f, c2 = 0.f, c3 = 0.f;
    int c = beg;
    for (; c + 8 <= end; c += 8) {
        int s0 = csr_src[c + 0], s1 = csr_src[c + 1], s2 = csr_src[c + 2], s3 = csr_src[c + 3];
        int s4 = csr_src[c + 4], s5 = csr_src[c + 5], s6 = csr_src[c + 6], s7 = csr_src[c + 7];
        int sA = q == 0 ? s0 : q == 1 ? s1 : q == 2 ? s2 : s3;
        int sB = q == 0 ? s4 : q == 1 ? s5 : q == 2 ? s6 : s7;
        uint2 vA = hv[(size_t)sA * 16 + i];
        uint2 vB = hv[(size_t)sB * 16 + i];
        a0 += bf_lo(vA.x); a1 += bf_hi(vA.x); a2 += bf_lo(vA.y); a3 += bf_hi(vA.y);
        c0 += bf_lo(vB.x); c1 += bf_hi(vB.x); c2 += bf_lo(vB.y); c3 += bf_hi(vB.y);
    }
    if (c + 4 <= end) {
        int s0 = csr_src[c + 0], s1 = csr_src[c + 1], s2 = csr_src[c + 2], s3 = csr_src[c + 3];
        int sA = q == 0 ? s0 : q == 1 ? s1 : q == 2 ? s2 : s3;
        uint2 vA = hv[(size_t)sA * 16 + i];
        a0 += bf_lo(vA.x); a1 += bf_hi(vA.x); a2 += bf_lo(vA.y); a3 += bf_hi(vA.y);
        c += 4;
    }
    if (c < end) {
        int r = end - c;
        int qq = (q < r) ? q : 0;
        int sA = csr_src[c + qq];
        uint2 vA = hv[(size_t)sA * 16 + i];
        if (q < r) {
            a0 += bf_lo(vA.x); a1 += bf_hi(vA.x); a2 += bf_lo(vA.y); a3 += bf_hi(vA.y);
        }
    }
    a0 += c0; a1 += c1; a2 += c2; a3 += c3;
    a0 += __shfl_xor(a0, 16); a1 += __shfl_xor(a1, 16);
    a2 += __shfl_xor(a2, 16); a3 += __shfl_xor(a3, 16);
    a0 += __shfl_xor(a0, 32); a1 += __shfl_xor(a1, 32);
    a2 += __shfl_xor(a2, 32); a3 += __shfl_xor(a3, 32);
    a0 += bf_lo(u_self.x); a1 += bf_hi(u_self.x);
    a2 += bf_lo(u_self.y); a3 += bf_hi(u_self.y);
    float dv = dinv[node];
    float4 bb = *(const float4*)(b + 4 * i);
    float v0 = fmaxf(a0 * dv + bb.x, 0.0f);
    float v1 = fmaxf(a1 * dv + bb.y, 0.0f);
    float v2 = fmaxf(a2 * dv + bb.z, 0.0f);
    float v3 = fmaxf(a3 * dv + bb.w, 0.0f);
    if (lane < 16) {
        uint2 o;
        o.x = pk_bf16(v0, v1);
        o.y = pk_bf16(v2, v3);
        ((uint2*)agg1)[(size_t)node * 16 + i] = o;
    }
}

// ================= layer 2 GEMM (MFMA bf16): h2s = bf16( (agg1b @ W2) * dinv ) =================

__global__ __launch_bounds__(256) void gemm2_mfma(const __hip_bfloat16* __restrict__ agg1b,
        const float* __restrict__ W, const float* __restrict__ dinv,
        __hip_bfloat16* __restrict__ h2, int n) {
    __shared__ unsigned As[64 * LDSU];
    int tid = threadIdx.x;
    int lane = tid & 63;
    int w = tid >> 6;
    int q = lane >> 4;
    int c = lane & 15;
    int nodeBase = blockIdx.x * 64;
    const unsigned* a1u = (const unsigned*)agg1b;

    #pragma unroll
    for (int i = 0; i < 8; ++i) {
        int uidx = tid + 256 * i;          // 0..2047
        int row = uidx >> 5, col = uidx & 31;
        int node = nodeBase + row; if (node >= n) node = n - 1;
        As[row * LDSU + col] = a1u[(size_t)node * 32 + col];
    }
    short8 Bf[3][2];
    #pragma unroll
    for (int nt = 0; nt < 3; ++nt) {
        int nn = nt * 16 + c;
        bool valid = (nn < 40);
        #pragma unroll
        for (int kk = 0; kk < 2; ++kk)
            #pragma unroll
            for (int j = 0; j < 8; ++j)
                Bf[nt][kk][j] = valid ? (short)bfbits(W[(kk * 32 + q * 8 + j) * 40 + nn]) : (short)0;
    }
    __syncthreads();

    f32x4 acc[3];
    #pragma unroll
    for (int nt = 0; nt < 3; ++nt) acc[nt] = (f32x4){0.f, 0.f, 0.f, 0.f};
    #pragma unroll
    for (int kk = 0; kk < 2; ++kk) {
        short8 a = *(const short8*)&As[(w * 16 + c) * LDSU + kk * 16 + q * 4];
        #pragma unroll
        for (int nt = 0; nt < 3; ++nt)
            acc[nt] = __builtin_amdgcn_mfma_f32_16x16x32_bf16(a, Bf[nt][kk], acc[nt], 0, 0, 0);
    }
    unsigned short* hu = (unsigned short*)h2;
    #pragma unroll
    for (int r = 0; r < 4; ++r) {
        int node = nodeBase + w * 16 + q * 4 + r;
        if (node < n) {
            float dv = dinv[node];
            #pragma unroll
            for (int nt = 0; nt < 3; ++nt) {
                int nn = nt * 16 + c;
                if (nn < 40)
                    hu[(size_t)node * H2S_STRIDE + nn] = bfbits(acc[nt][r] * dv);
            }
        }
    }
}

// ================= gather layer 2 + fused log_softmax (quarter-wave) =================
// Row = 40 bf16 in a 64-element (128 B) stride; lane i covers features 4i..4i+3,
// valid for i<10. After the quarter combine all 4 quarters hold identical sums, so
// ONLY quarter 0 (act = lane<10) contributes to the softmax sum — each feature once.

__global__ __launch_bounds__(256) void gather2_kernel(const __hip_bfloat16* __restrict__ h2s,
        const int* __restrict__ rowstart, const int* __restrict__ csr_src,
        const float* __restrict__ dinv, const float* __restrict__ b,
        float* __restrict__ out, int n) {
    int tid = threadIdx.x;
    int node_nu = blockIdx.x * 4 + (tid >> 6);
    if (node_nu >= n) return;
    int node = __builtin_amdgcn_readfirstlane(node_nu);
    int lane = tid & 63;
    int q = lane >> 4;
    int i = lane & 15;
    int ic = (i < 10) ? i : 9;     // clamp within valid 40-feature region (same line)
    const uint2* hv = (const uint2*)h2s;     // 16 uint2 per padded row
    uint2 u_self = hv[(size_t)node * 16 + ic];
    int beg = rowstart[node], end = rowstart[node + 1];
    float a0 = 0.f, a1 = 0.f, a2 = 0.f, a3 = 0.f;
    float c0 = 0.f, c1 = 0.f, c2 = 0.f, c3 = 0.f;
    int c = beg;
    for (; c + 8 <= end; c += 8) {
        int s0 = csr_src[c + 0], s1 = csr_src[c + 1], s2 = csr_src[c + 2], s3 = csr_src[c + 3];
        int s4 = csr_src[c + 4], s5 = csr_src[c + 5], s6 = csr_src[c + 6], s7 = csr_src[c + 7];
        int sA = q == 0 ? s0 : q == 1 ? s1 : q == 2 ? s2 : s3;
        int sB = q == 0 ? s4 : q == 1 ? s5 : q == 2 ? s6 : s7;
        uint2 vA = hv[(size_t)sA * 16 + ic];
        uint2 vB = hv[(size_t)sB * 16 + ic];
        a0 += bf_lo(vA.x); a1 += bf_hi(vA.x); a2 += bf_lo(vA.y); a3 += bf_hi(vA.y);
        c0 += bf_lo(vB.x); c1 += bf_hi(vB.x); c2 += bf_lo(vB.y); c3 += bf_hi(vB.y);
    }
    if (c + 4 <= end) {
        int s0 = csr_src[c + 0], s1 = csr_src[c + 1], s2 = csr_src[c + 2], s3 = csr_src[c + 3];
        int sA = q == 0 ? s0 : q == 1 ? s1 : q == 2 ? s2 : s3;
        uint2 vA = hv[(size_t)sA * 16 + ic];
        a0 += bf_lo(vA.x); a1 += bf_hi(vA.x); a2 += bf_lo(vA.y); a3 += bf_hi(vA.y);
        c += 4;
    }
    if (c < end) {
        int r = end - c;
        int qq = (q < r) ? q : 0;
        int sA = csr_src[c + qq];
        uint2 vA = hv[(size_t)sA * 16 + ic];
        if (q < r) {
            a0 += bf_lo(vA.x); a1 += bf_hi(vA.x); a2 += bf_lo(vA.y); a3 += bf_hi(vA.y);
        }
    }
    a0 += c0; a1 += c1; a2 += c2; a3 += c3;
    a0 += __shfl_xor(a0, 16); a1 += __shfl_xor(a1, 16);
    a2 += __shfl_xor(a2, 16); a3 += __shfl_xor(a3, 16);
    a0 += __shfl_xor(a0, 32); a1 += __shfl_xor(a1, 32);
    a2 += __shfl_xor(a2, 32); a3 += __shfl_xor(a3, 32);
    a0 += bf_lo(u_self.x); a1 += bf_hi(u_self.x);
    a2 += bf_lo(u_self.y); a3 += bf_hi(u_self.y);
    float dv = dinv[node];
    float4 bb = *(const float4*)(b + 4 * ic);
    float v0 = a0 * dv + bb.x;
    float v1 = a1 * dv + bb.y;
    float v2 = a2 * dv + bb.z;
    float v3 = a3 * dv + bb.w;
    // log_softmax over 40 features: quarter 0 only (each feature exactly once)
    bool act = (lane < 10);
    float mx = act ? fmaxf(fmaxf(v0, v1), fmaxf(v2, v3)) : -INFINITY;
    #pragma unroll
    for (int off = 32; off; off >>= 1) mx = fmaxf(mx, __shfl_xor(mx, off));
    float sm = act ? (expf(v0 - mx) + expf(v1 - mx) + expf(v2 - mx) + expf(v3 - mx)) : 0.0f;
    #pragma unroll
    for (int off = 32; off; off >>= 1) sm += __shfl_xor(sm, off);
    float ls = mx + logf(sm);
    if (lane < 10)   // q==0 && i<10
        *(float4*)(out + (size_t)node * 40 + 4 * i) =
            make_float4(v0 - ls, v1 - ls, v2 - ls, v3 - ls);
}

extern "C" void kernel_launch(void* const* d_in, const int* in_sizes, int n_in,
                              void* d_out, int out_size, void* d_ws, size_t ws_size,
                              hipStream_t stream) {
    const float* x  = (const float*)d_in[0];
    const int*   ei = (const int*)d_in[1];
    const float* W1 = (const float*)d_in[2];
    const float* b1 = (const float*)d_in[3];
    const float* W2 = (const float*)d_in[4];
    const float* b2 = (const float*)d_in[5];
    float* out = (float*)d_out;

    int N = in_sizes[0] / FIN;     // 100000
    int E = in_sizes[1] / 2;       // 800000
    const int* src = ei;
    const int* dst = ei + E;

    int nbuck = (N + 255) >> 8;              // 391
    int nblkc = (E + CCHUNK - 1) / CCHUNK;   // 196

    char* ws = (char*)d_ws;
    size_t off = 0;
    auto alloc = [&](size_t bytes) {
        void* p = ws + off;
        off = (off + bytes + 255) & ~(size_t)255;
        return p;
    };
    int*             cnt       = (int*)alloc((size_t)nbuck * nblkc * 4);
    int*             total     = (int*)alloc((size_t)nbuck * 4);
    int*             bstart    = (int*)alloc((size_t)(nbuck + 1) * 4);
    unsigned*        ebuf      = (unsigned*)alloc((size_t)E * 4);
    int*             rowstart  = (int*)alloc((size_t)(N + 1) * 4);
    float*           dinv      = (float*)alloc((size_t)N * 4);
    int*             csr_src   = (int*)alloc((size_t)E * 4);
    __hip_bfloat16*  h1s       = (__hip_bfloat16*)alloc((size_t)N * FIN * 2);
    __hip_bfloat16*  agg1b     = (__hip_bfloat16*)alloc((size_t)N * HID * 2);
    __hip_bfloat16*  h2s       = (__hip_bfloat16*)alloc((size_t)N * H2S_STRIDE * 2);

    int gblocks = (N + 63) / 64;   // 1563

    bucket_hist_kernel<<<nblkc, 256, 0, stream>>>(dst, cnt, E, nbuck, nblkc);
    bucket_colscan_kernel<<<nbuck, 256, 0, stream>>>(cnt, total, nblkc);
    bucket_scan_kernel<<<1, 512, 0, stream>>>(total, bstart, nbuck, rowstart, N);
    partition_kernel<<<nblkc, 256, 0, stream>>>(src, dst, cnt, bstart, ebuf, E, nbuck, nblkc);
    build_csr_kernel<<<nbuck, 256, 0, stream>>>(ebuf, bstart, rowstart, dinv, csr_src, N);
    gemm1_mfma<<<gblocks, 256, 0, stream>>>(x, W1, dinv, h1s, N);
    gather1_kernel<<<(N + 3) / 4, 256, 0, stream>>>(h1s, rowstart, csr_src, dinv, b1, agg1b, N);
    gemm2_mfma<<<gblocks, 256, 0, stream>>>(agg1b, W2, dinv, h2s, N);
    gather2_kernel<<<(N + 3) / 4, 256, 0, stream>>>(h2s, rowstart, csr_src, dinv, b2, out, N);
}

// Round 10
// 199.935 us; speedup vs baseline: 1.0082x; 1.0082x over previous
//
#include <hip/hip_runtime.h>
#include <hip/hip_fp16.h>
#include <math.h>

#define FIN 64
#define HID 64
#define FOUT 40
#define H2S_STRIDE 64   // fp16 elements; 128 B row stride, one cache line per row
#define LDSU 36         // uint stride per staged LDS row (144 B): pad breaks conflicts
#define CCHUNK 4096     // edges per partition block
#define MAXBUCK 400     // LDS histogram capacity (>= nbuck = ceil(N/256))

typedef __attribute__((ext_vector_type(8))) short short8;
typedef __attribute__((ext_vector_type(4))) float f32x4;

__device__ __forceinline__ __half2 u2h(unsigned u) { return *(__half2*)&u; }
__device__ __forceinline__ unsigned h2u(__half2 h) { return *(unsigned*)&h; }
__device__ __forceinline__ __half2 shfl_xor_h2(__half2 v, int off) {
    int b = *(int*)&v;
    b = __shfl_xor(b, off);
    return *(__half2*)&b;
}

// ================= CSR build: two-level counting sort (no global atomics) =================
// bucket = dst >> 8 (256 nodes per bucket). Pack: src (20 bits) | local_dst << 20.

__global__ __launch_bounds__(256) void bucket_hist_kernel(const int* __restrict__ dst,
        int* __restrict__ cnt, int E, int nbuck, int nblkc) {
    __shared__ int hist[MAXBUCK];
    int tid = threadIdx.x;
    for (int i = tid; i < nbuck; i += 256) hist[i] = 0;
    __syncthreads();
    int base = blockIdx.x * CCHUNK;
    int lim = min(CCHUNK, E - base);
    for (int i = tid; i < lim; i += 256)
        atomicAdd(&hist[dst[base + i] >> 8], 1);
    __syncthreads();
    for (int b = tid; b < nbuck; b += 256)
        cnt[b * nblkc + blockIdx.x] = hist[b];
}

__global__ __launch_bounds__(256) void bucket_colscan_kernel(int* __restrict__ cnt,
        int* __restrict__ total, int nblkc) {
    int b = blockIdx.x;
    int tid = threadIdx.x, lane = tid & 63, wid = tid >> 6;
    int v = (tid < nblkc) ? cnt[b * nblkc + tid] : 0;
    int incl = v;
    #pragma unroll
    for (int off = 1; off < 64; off <<= 1) {
        int t2 = __shfl_up(incl, off);
        if (lane >= off) incl += t2;
    }
    __shared__ int ws[4];
    if (lane == 63) ws[wid] = incl;
    __syncthreads();
    int woff = 0;
    for (int w2 = 0; w2 < wid; ++w2) woff += ws[w2];
    int excl = woff + incl - v;
    if (tid < nblkc) cnt[b * nblkc + tid] = excl;
    if (tid == 255) total[b] = woff + incl;
}

__global__ __launch_bounds__(512) void bucket_scan_kernel(const int* __restrict__ total,
        int* __restrict__ bucketStart, int nbuck, int* __restrict__ rowstart, int N) {
    int tid = threadIdx.x, lane = tid & 63, wid = tid >> 6;
    int v = (tid < nbuck) ? total[tid] : 0;
    int incl = v;
    #pragma unroll
    for (int off = 1; off < 64; off <<= 1) {
        int t2 = __shfl_up(incl, off);
        if (lane >= off) incl += t2;
    }
    __shared__ int ws[8];
    if (lane == 63) ws[wid] = incl;
    __syncthreads();
    int woff = 0;
    for (int w2 = 0; w2 < wid; ++w2) woff += ws[w2];
    int excl = woff + incl - v;
    if (tid <= nbuck) bucketStart[tid] = excl;
    if (tid == nbuck) rowstart[N] = excl;     // == E
}

__global__ __launch_bounds__(256) void partition_kernel(const int* __restrict__ src,
        const int* __restrict__ dst, const int* __restrict__ cnt,
        const int* __restrict__ bucketStart, unsigned* __restrict__ ebuf,
        int E, int nbuck, int nblkc) {
    __shared__ int cur[MAXBUCK];
    int tid = threadIdx.x;
    int r = blockIdx.x;
    for (int b = tid; b < nbuck; b += 256)
        cur[b] = bucketStart[b] + cnt[b * nblkc + r];
    __syncthreads();
    int base = r * CCHUNK;
    int lim = min(CCHUNK, E - base);
    for (int i = tid; i < lim; i += 256) {
        int d = dst[base + i];
        int s = src[base + i];
        int b = d >> 8;
        int pos = atomicAdd(&cur[b], 1);       // LDS atomic
        ebuf[pos] = (unsigned)s | ((unsigned)(d & 255) << 20);
    }
}

__global__ __launch_bounds__(256) void build_csr_kernel(const unsigned* __restrict__ ebuf,
        const int* __restrict__ bucketStart, int* __restrict__ rowstart,
        float* __restrict__ dinv, int* __restrict__ csr_src, int n) {
    __shared__ int hist[256];
    __shared__ int cur[256];
    __shared__ int ws[4];
    __shared__ int stage[4096];
    int b = blockIdx.x, tid = threadIdx.x;
    int base = bucketStart[b];
    int m = bucketStart[b + 1] - base;
    hist[tid] = 0;
    __syncthreads();
    for (int i = tid; i < m; i += 256)
        atomicAdd(&hist[ebuf[base + i] >> 20], 1);
    __syncthreads();
    int deg = hist[tid];
    int lane = tid & 63, wid = tid >> 6;
    int incl = deg;
    #pragma unroll
    for (int off = 1; off < 64; off <<= 1) {
        int t2 = __shfl_up(incl, off);
        if (lane >= off) incl += t2;
    }
    if (lane == 63) ws[wid] = incl;
    __syncthreads();
    int woff = 0;
    for (int w2 = 0; w2 < wid; ++w2) woff += ws[w2];
    int excl = woff + incl - deg;
    int node = b * 256 + tid;
    if (node < n) {
        rowstart[node] = base + excl;
        dinv[node] = rsqrtf((float)deg + 1.0f);
    }
    cur[tid] = excl;
    __syncthreads();
    if (m <= 4096) {
        for (int i = tid; i < m; i += 256) {
            unsigned p = ebuf[base + i];
            int pos = atomicAdd(&cur[p >> 20], 1);
            stage[pos] = (int)(p & 0xFFFFFu);
        }
        __syncthreads();
        for (int i = tid; i < m; i += 256)
            csr_src[base + i] = stage[i];      // coalesced
    } else {
        for (int i = tid; i < m; i += 256) {
            unsigned p = ebuf[base + i];
            int pos = atomicAdd(&cur[p >> 20], 1);
            csr_src[base + pos] = (int)(p & 0xFFFFFu);
        }
    }
}

// ================= layer 1 GEMM (MFMA f16): h1s = f16( (x @ W1) * dinv ) =================

__global__ __launch_bounds__(256) void gemm1_mfma(const float* __restrict__ x,
        const float* __restrict__ W, const float* __restrict__ dinv,
        __half* __restrict__ h, int n) {
    __shared__ unsigned As[64 * LDSU];
    int tid = threadIdx.x;
    int lane = tid & 63;
    int w = tid >> 6;
    int q = lane >> 4;        // 0..3 k-block / row-quad
    int c = lane & 15;        // col within tile
    int nodeBase = blockIdx.x * 64;

    #pragma unroll
    for (int i = 0; i < 4; ++i) {
        int fidx = tid + 256 * i;          // float4 index 0..1023
        int row = fidx >> 4, c4 = fidx & 15;
        int node = nodeBase + row; if (node >= n) node = n - 1;
        float4 v = *(const float4*)(x + (size_t)node * 64 + c4 * 4);
        __half2 p0 = __floats2half2_rn(v.x, v.y);
        __half2 p1 = __floats2half2_rn(v.z, v.w);
        As[row * LDSU + c4 * 2 + 0] = h2u(p0);
        As[row * LDSU + c4 * 2 + 1] = h2u(p1);
    }
    short8 Bf[4][2];
    #pragma unroll
    for (int nt = 0; nt < 4; ++nt)
        #pragma unroll
        for (int kk = 0; kk < 2; ++kk)
            #pragma unroll
            for (int j = 0; j < 8; ++j)
                Bf[nt][kk][j] = (short)__half_as_ushort(
                    __float2half(W[(kk * 32 + q * 8 + j) * 64 + nt * 16 + c]));
    __syncthreads();

    f32x4 acc[4];
    #pragma unroll
    for (int nt = 0; nt < 4; ++nt) acc[nt] = (f32x4){0.f, 0.f, 0.f, 0.f};
    #pragma unroll
    for (int kk = 0; kk < 2; ++kk) {
        short8 a = *(const short8*)&As[(w * 16 + c) * LDSU + kk * 16 + q * 4];
        #pragma unroll
        for (int nt = 0; nt < 4; ++nt)
            acc[nt] = __builtin_amdgcn_mfma_f32_16x16x32_f16(a, Bf[nt][kk], acc[nt], 0, 0, 0);
    }
    unsigned short* hu = (unsigned short*)h;
    #pragma unroll
    for (int r = 0; r < 4; ++r) {
        int node = nodeBase + w * 16 + q * 4 + r;
        if (node < n) {
            float dv = dinv[node];
            #pragma unroll
            for (int nt = 0; nt < 4; ++nt)
                hu[(size_t)node * 64 + nt * 16 + c] =
                    __half_as_ushort(__float2half(acc[nt][r] * dv));
        }
    }
}

// ================= gather layer 1 (quarter-wave, packed fp16 accumulate) =========
// agg1h[d] = f16( relu( (h1s[d] + sum_{e->d} h1s[src]) * dinv[d] + b1 ) )
// 16-lane quarter q loads edge (c+q)'s full 128 B row as uint2 (4 fp16 features);
// accumulate with v_pk_add_f16; combine quarters with shfl_xor + pk_add.

__global__ __launch_bounds__(256) void gather1_kernel(const __half* __restrict__ h1s,
        const int* __restrict__ rowstart, const int* __restrict__ csr_src,
        const float* __restrict__ dinv, const float* __restrict__ b,
        __half* __restrict__ agg1, int n) {
    int tid = threadIdx.x;
    int node_nu = blockIdx.x * 4 + (tid >> 6);
    if (node_nu >= n) return;
    int node = __builtin_amdgcn_readfirstlane(node_nu);
    int lane = tid & 63;
    int q = lane >> 4;             // quarter 0..3 = which edge in the group
    int i = lane & 15;             // uint2 index within row (features 4i..4i+3)
    const uint2* hv = (const uint2*)h1s;     // 16 uint2 per row
    uint2 u_self = hv[(size_t)node * 16 + i];
    int beg = rowstart[node], end = rowstart[node + 1];
    __half2 aAx = u2h(0u), aAy = u2h(0u), aBx = u2h(0u), aBy = u2h(0u);
    int c = beg;
    for (; c + 8 <= end; c += 8) {
        int s0 = csr_src[c + 0], s1 = csr_src[c + 1], s2 = csr_src[c + 2], s3 = csr_src[c + 3];
        int s4 = csr_src[c + 4], s5 = csr_src[c + 5], s6 = csr_src[c + 6], s7 = csr_src[c + 7];
        int sA = q == 0 ? s0 : q == 1 ? s1 : q == 2 ? s2 : s3;
        int sB = q == 0 ? s4 : q == 1 ? s5 : q == 2 ? s6 : s7;
        uint2 vA = hv[(size_t)sA * 16 + i];
        uint2 vB = hv[(size_t)sB * 16 + i];
        aAx = __hadd2(aAx, u2h(vA.x)); aAy = __hadd2(aAy, u2h(vA.y));
        aBx = __hadd2(aBx, u2h(vB.x)); aBy = __hadd2(aBy, u2h(vB.y));
    }
    if (c + 4 <= end) {
        int s0 = csr_src[c + 0], s1 = csr_src[c + 1], s2 = csr_src[c + 2], s3 = csr_src[c + 3];
        int sA = q == 0 ? s0 : q == 1 ? s1 : q == 2 ? s2 : s3;
        uint2 vA = hv[(size_t)sA * 16 + i];
        aAx = __hadd2(aAx, u2h(vA.x)); aAy = __hadd2(aAy, u2h(vA.y));
        c += 4;
    }
    if (c < end) {
        int r = end - c;
        int qq = (q < r) ? q : 0;
        int sA = csr_src[c + qq];
        uint2 vA = hv[(size_t)sA * 16 + i];
        if (q < r) {
            aAx = __hadd2(aAx, u2h(vA.x)); aAy = __hadd2(aAy, u2h(vA.y));
        }
    }
    aAx = __hadd2(aAx, aBx); aAy = __hadd2(aAy, aBy);
    aAx = __hadd2(aAx, shfl_xor_h2(aAx, 16)); aAy = __hadd2(aAy, shfl_xor_h2(aAy, 16));
    aAx = __hadd2(aAx, shfl_xor_h2(aAx, 32)); aAy = __hadd2(aAy, shfl_xor_h2(aAy, 32));
    aAx = __hadd2(aAx, u2h(u_self.x)); aAy = __hadd2(aAy, u2h(u_self.y));
    float2 fx = __half22float2(aAx);
    float2 fy = __half22float2(aAy);
    float dv = dinv[node];
    float4 bb = *(const float4*)(b + 4 * i);
    float v0 = fmaxf(fx.x * dv + bb.x, 0.0f);
    float v1 = fmaxf(fx.y * dv + bb.y, 0.0f);
    float v2 = fmaxf(fy.x * dv + bb.z, 0.0f);
    float v3 = fmaxf(fy.y * dv + bb.w, 0.0f);
    if (lane < 16) {
        uint2 o;
        o.x = h2u(__floats2half2_rn(v0, v1));
        o.y = h2u(__floats2half2_rn(v2, v3));
        ((uint2*)agg1)[(size_t)node * 16 + i] = o;
    }
}

// ================= layer 2 GEMM (MFMA f16): h2s = f16( (agg1h @ W2) * dinv ) =================

__global__ __launch_bounds__(256) void gemm2_mfma(const __half* __restrict__ agg1h,
        const float* __restrict__ W, const float* __restrict__ dinv,
        __half* __restrict__ h2, int n) {
    __shared__ unsigned As[64 * LDSU];
    int tid = threadIdx.x;
    int lane = tid & 63;
    int w = tid >> 6;
    int q = lane >> 4;
    int c = lane & 15;
    int nodeBase = blockIdx.x * 64;
    const unsigned* a1u = (const unsigned*)agg1h;

    #pragma unroll
    for (int i = 0; i < 8; ++i) {
        int uidx = tid + 256 * i;          // 0..2047
        int row = uidx >> 5, col = uidx & 31;
        int node = nodeBase + row; if (node >= n) node = n - 1;
        As[row * LDSU + col] = a1u[(size_t)node * 32 + col];
    }
    short8 Bf[3][2];
    #pragma unroll
    for (int nt = 0; nt < 3; ++nt) {
        int nn = nt * 16 + c;
        bool valid = (nn < 40);
        #pragma unroll
        for (int kk = 0; kk < 2; ++kk)
            #pragma unroll
            for (int j = 0; j < 8; ++j)
                Bf[nt][kk][j] = valid ? (short)__half_as_ushort(
                    __float2half(W[(kk * 32 + q * 8 + j) * 40 + nn])) : (short)0;
    }
    __syncthreads();

    f32x4 acc[3];
    #pragma unroll
    for (int nt = 0; nt < 3; ++nt) acc[nt] = (f32x4){0.f, 0.f, 0.f, 0.f};
    #pragma unroll
    for (int kk = 0; kk < 2; ++kk) {
        short8 a = *(const short8*)&As[(w * 16 + c) * LDSU + kk * 16 + q * 4];
        #pragma unroll
        for (int nt = 0; nt < 3; ++nt)
            acc[nt] = __builtin_amdgcn_mfma_f32_16x16x32_f16(a, Bf[nt][kk], acc[nt], 0, 0, 0);
    }
    unsigned short* hu = (unsigned short*)h2;
    #pragma unroll
    for (int r = 0; r < 4; ++r) {
        int node = nodeBase + w * 16 + q * 4 + r;
        if (node < n) {
            float dv = dinv[node];
            #pragma unroll
            for (int nt = 0; nt < 3; ++nt) {
                int nn = nt * 16 + c;
                if (nn < 40)
                    hu[(size_t)node * H2S_STRIDE + nn] =
                        __half_as_ushort(__float2half(acc[nt][r] * dv));
            }
        }
    }
}

// ================= gather layer 2 + fused log_softmax (quarter-wave, packed fp16) =====
// Row = 40 fp16 in a 64-element (128 B) stride; lane i covers features 4i..4i+3,
// valid for i<10. After the quarter combine all 4 quarters hold identical sums, so
// ONLY quarter 0 (act = lane<10) contributes to the softmax sum — each feature once.

__global__ __launch_bounds__(256) void gather2_kernel(const __half* __restrict__ h2s,
        const int* __restrict__ rowstart, const int* __restrict__ csr_src,
        const float* __restrict__ dinv, const float* __restrict__ b,
        float* __restrict__ out, int n) {
    int tid = threadIdx.x;
    int node_nu = blockIdx.x * 4 + (tid >> 6);
    if (node_nu >= n) return;
    int node = __builtin_amdgcn_readfirstlane(node_nu);
    int lane = tid & 63;
    int q = lane >> 4;
    int i = lane & 15;
    int ic = (i < 10) ? i : 9;     // clamp within valid 40-feature region (same line)
    const uint2* hv = (const uint2*)h2s;     // 16 uint2 per padded row
    uint2 u_self = hv[(size_t)node * 16 + ic];
    int beg = rowstart[node], end = rowstart[node + 1];
    __half2 aAx = u2h(0u), aAy = u2h(0u), aBx = u2h(0u), aBy = u2h(0u);
    int c = beg;
    for (; c + 8 <= end; c += 8) {
        int s0 = csr_src[c + 0], s1 = csr_src[c + 1], s2 = csr_src[c + 2], s3 = csr_src[c + 3];
        int s4 = csr_src[c + 4], s5 = csr_src[c + 5], s6 = csr_src[c + 6], s7 = csr_src[c + 7];
        int sA = q == 0 ? s0 : q == 1 ? s1 : q == 2 ? s2 : s3;
        int sB = q == 0 ? s4 : q == 1 ? s5 : q == 2 ? s6 : s7;
        uint2 vA = hv[(size_t)sA * 16 + ic];
        uint2 vB = hv[(size_t)sB * 16 + ic];
        aAx = __hadd2(aAx, u2h(vA.x)); aAy = __hadd2(aAy, u2h(vA.y));
        aBx = __hadd2(aBx, u2h(vB.x)); aBy = __hadd2(aBy, u2h(vB.y));
    }
    if (c + 4 <= end) {
        int s0 = csr_src[c + 0], s1 = csr_src[c + 1], s2 = csr_src[c + 2], s3 = csr_src[c + 3];
        int sA = q == 0 ? s0 : q == 1 ? s1 : q == 2 ? s2 : s3;
        uint2 vA = hv[(size_t)sA * 16 + ic];
        aAx = __hadd2(aAx, u2h(vA.x)); aAy = __hadd2(aAy, u2h(vA.y));
        c += 4;
    }
    if (c < end) {
        int r = end - c;
        int qq = (q < r) ? q : 0;
        int sA = csr_src[c + qq];
        uint2 vA = hv[(size_t)sA * 16 + ic];
        if (q < r) {
            aAx = __hadd2(aAx, u2h(vA.x)); aAy = __hadd2(aAy, u2h(vA.y));
        }
    }
    aAx = __hadd2(aAx, aBx); aAy = __hadd2(aAy, aBy);
    aAx = __hadd2(aAx, shfl_xor_h2(aAx, 16)); aAy = __hadd2(aAy, shfl_xor_h2(aAy, 16));
    aAx = __hadd2(aAx, shfl_xor_h2(aAx, 32)); aAy = __hadd2(aAy, shfl_xor_h2(aAy, 32));
    aAx = __hadd2(aAx, u2h(u_self.x)); aAy = __hadd2(aAy, u2h(u_self.y));
    float2 fx = __half22float2(aAx);
    float2 fy = __half22float2(aAy);
    float dv = dinv[node];
    float4 bb = *(const float4*)(b + 4 * ic);
    float v0 = fx.x * dv + bb.x;
    float v1 = fx.y * dv + bb.y;
    float v2 = fy.x * dv + bb.z;
    float v3 = fy.y * dv + bb.w;
    // log_softmax over 40 features: quarter 0 only (each feature exactly once)
    bool act = (lane < 10);
    float mx = act ? fmaxf(fmaxf(v0, v1), fmaxf(v2, v3)) : -INFINITY;
    #pragma unroll
    for (int off = 32; off; off >>= 1) mx = fmaxf(mx, __shfl_xor(mx, off));
    float sm = act ? (expf(v0 - mx) + expf(v1 - mx) + expf(v2 - mx) + expf(v3 - mx)) : 0.0f;
    #pragma unroll
    for (int off = 32; off; off >>= 1) sm += __shfl_xor(sm, off);
    float ls = mx + logf(sm);
    if (lane < 10)   // q==0 && i<10
        *(float4*)(out + (size_t)node * 40 + 4 * i) =
            make_float4(v0 - ls, v1 - ls, v2 - ls, v3 - ls);
}

extern "C" void kernel_launch(void* const* d_in, const int* in_sizes, int n_in,
                              void* d_out, int out_size, void* d_ws, size_t ws_size,
                              hipStream_t stream) {
    const float* x  = (const float*)d_in[0];
    const int*   ei = (const int*)d_in[1];
    const float* W1 = (const float*)d_in[2];
    const float* b1 = (const float*)d_in[3];
    const float* W2 = (const float*)d_in[4];
    const float* b2 = (const float*)d_in[5];
    float* out = (float*)d_out;

    int N = in_sizes[0] / FIN;     // 100000
    int E = in_sizes[1] / 2;       // 800000
    const int* src = ei;
    const int* dst = ei + E;

    int nbuck = (N + 255) >> 8;              // 391
    int nblkc = (E + CCHUNK - 1) / CCHUNK;   // 196

    char* ws = (char*)d_ws;
    size_t off = 0;
    auto alloc = [&](size_t bytes) {
        void* p = ws + off;
        off = (off + bytes + 255) & ~(size_t)255;
        return p;
    };
    int*       cnt       = (int*)alloc((size_t)nbuck * nblkc * 4);
    int*       total     = (int*)alloc((size_t)nbuck * 4);
    int*       bstart    = (int*)alloc((size_t)(nbuck + 1) * 4);
    unsigned*  ebuf      = (unsigned*)alloc((size_t)E * 4);
    int*       rowstart  = (int*)alloc((size_t)(N + 1) * 4);
    float*     dinv      = (float*)alloc((size_t)N * 4);
    int*       csr_src   = (int*)alloc((size_t)E * 4);
    __half*    h1s       = (__half*)alloc((size_t)N * FIN * 2);
    __half*    agg1h     = (__half*)alloc((size_t)N * HID * 2);
    __half*    h2s       = (__half*)alloc((size_t)N * H2S_STRIDE * 2);

    int gblocks = (N + 63) / 64;   // 1563

    bucket_hist_kernel<<<nblkc, 256, 0, stream>>>(dst, cnt, E, nbuck, nblkc);
    bucket_colscan_kernel<<<nbuck, 256, 0, stream>>>(cnt, total, nblkc);
    bucket_scan_kernel<<<1, 512, 0, stream>>>(total, bstart, nbuck, rowstart, N);
    partition_kernel<<<nblkc, 256, 0, stream>>>(src, dst, cnt, bstart, ebuf, E, nbuck, nblkc);
    build_csr_kernel<<<nbuck, 256, 0, stream>>>(ebuf, bstart, rowstart, dinv, csr_src, N);
    gemm1_mfma<<<gblocks, 256, 0, stream>>>(x, W1, dinv, h1s, N);
    gather1_kernel<<<(N + 3) / 4, 256, 0, stream>>>(h1s, rowstart, csr_src, dinv, b1, agg1h, N);
    gemm2_mfma<<<gblocks, 256, 0, stream>>>(agg1h, W2, dinv, h2s, N);
    gather2_kernel<<<(N + 3) / 4, 256, 0, stream>>>(h2s, rowstart, csr_src, dinv, b2, out, N);
}